// Round 6
// baseline (569.048 us; speedup 1.0000x reference)
//
#include <hip/hip_runtime.h>
#include <hip/hip_fp16.h>
#include <math.h>

#define N_CELLS 16384
#define HID 512
#define IND 512
#define KNB 15
#define NCOPY 64

#define ROT_BLOCKS  8192    // N*H/4 elems / 256 threads
#define PUMP_BLOCKS 4096    // 4 cells per block (wave per cell)
#define ZERO_BLOCKS 64      // 64*256 float4 = 65536 floats (emis)

// ---- workspace layout (bytes) ----
#define CNT_OFF   0                                   // int: last-block counter for k_fin
#define EMIS_OFF  128                                 // float[NCOPY][1024]: emission partials (re[512], im[512])
#define LAS_OFF   (EMIS_OFF + NCOPY*1024*4)           // int[N_CELLS]: lasing flags
#define CAV_OFF   (LAS_OFF + N_CELLS*4)               // float[1536]: cav_new_re, cav_new_im, cav_phase
#define VPART_OFF (CAV_OFF + 1536*4)                  // float2[N_CELLS]: per-cell (sum_a, sum_a2) partials
#define ROT_OFF   (1<<20)                             // planar fp16: per row, 256 groups of {re-pair, im-pair}
#define NST_OFF   (ROT_OFF + (size_t)N_CELLS*HID*4)   // same layout, new_states

__device__ inline __half2 f2h2(float f) { union { float f; __half2 h; } u; u.f = f; return u.h; }
__device__ inline float   h22f(__half2 h) { union { float f; __half2 h; } u; u.h = h; return u.f; }

// ---------------------------------------------------------------------------
// Kernel 1 (fused front): phase rotation (planar fp16 out) + pump/lasing +
// emis zeroing + counter zeroing.
__global__ __launch_bounds__(256) void k_front(const float* __restrict__ cr,
                                               const float* __restrict__ ci,
                                               const float* __restrict__ pv,
                                               float4* __restrict__ rot,
                                               const float* __restrict__ x,
                                               const float* __restrict__ pW,
                                               const float* __restrict__ pb,
                                               const float* __restrict__ excited,
                                               int* __restrict__ lasing,
                                               float* __restrict__ emis,
                                               int* __restrict__ cnt) {
    int b = blockIdx.x;
    int tid = threadIdx.x;
    if (b < ROT_BLOCKS) {
        // ---- rotate by exp(i*0.1*pv), 4 channels/thread, planar pack ----
        int i = b * 256 + tid;
        const float4* cr4 = (const float4*)cr;
        const float4* ci4 = (const float4*)ci;
        const float4* pv4 = (const float4*)pv;
        float4 a = cr4[i], bb = ci4[i], t = pv4[i];
        float s0, c0, s1, c1, s2, c2, s3, c3;
        __sincosf(0.1f * t.x, &s0, &c0);
        __sincosf(0.1f * t.y, &s1, &c1);
        __sincosf(0.1f * t.z, &s2, &c2);
        __sincosf(0.1f * t.w, &s3, &c3);
        float re0 = a.x * c0 - bb.x * s0, im0 = a.x * s0 + bb.x * c0;
        float re1 = a.y * c1 - bb.y * s1, im1 = a.y * s1 + bb.y * c1;
        float re2 = a.z * c2 - bb.z * s2, im2 = a.z * s2 + bb.z * c2;
        float re3 = a.w * c3 - bb.w * s3, im3 = a.w * s3 + bb.w * c3;
        // planar: {re01, im01, re23, im23}
        rot[i] = make_float4(h22f(__floats2half2_rn(re0, re1)),
                             h22f(__floats2half2_rn(im0, im1)),
                             h22f(__floats2half2_rn(re2, re3)),
                             h22f(__floats2half2_rn(im2, im3)));
    } else if (b < ROT_BLOCKS + PUMP_BLOCKS) {
        // ---- pump = sigmoid(x . pump_W[cell] + pb); lasing flag. Wave/cell ----
        int gtid = (b - ROT_BLOCKS) * 256 + tid;
        int cell = gtid >> 6;
        int lane = gtid & 63;
        const float4* w4 = (const float4*)(pW + (size_t)cell * IND);
        const float4* x4 = (const float4*)x;
        float acc = 0.f;
#pragma unroll
        for (int t = 0; t < (IND / 4) / 64; ++t) {   // 2 iters
            float4 a = w4[lane + 64 * t];
            float4 bx = x4[lane + 64 * t];
            acc += a.x * bx.x + a.y * bx.y + a.z * bx.z + a.w * bx.w;
        }
#pragma unroll
        for (int o = 32; o; o >>= 1) acc += __shfl_xor(acc, o, 64);
        if (lane == 0) {
            float p = 1.f / (1.f + expf(-(acc + pb[cell])));
            float e = excited[cell] * 0.95f + p * 0.05f;
            e = fminf(fmaxf(e, 0.f), 1.f);
            lasing[cell] = (e > 0.5f) ? 1 : 0;
        }
    } else {
        // ---- zero emission accumulators + last-block counter ----
        int zb = b - ROT_BLOCKS - PUMP_BLOCKS;
        int idx = zb * 256 + tid;
        ((float4*)emis)[idx] = make_float4(0.f, 0.f, 0.f, 0.f);
        if (zb == 0 && tid == 0) *cnt = 0;
    }
}

// ---------------------------------------------------------------------------
// Kernel 2: neighbor coupling, planar fp16, packed-half inner loop (no perms).
// Block = 1 cell, natural dispatch order (round-3 lesson: do NOT swizzle).
// 256 threads, 2 channels/thread; per gather: one 8B load -> (re-pair, im-pair).
__global__ __launch_bounds__(256) void k_coup(const float2* __restrict__ rot2,
                                              const int* __restrict__ nbrs,
                                              const int* __restrict__ lasing,
                                              float2* __restrict__ nst2,
                                              float* __restrict__ emis) {
    __shared__ int nb[KNB];
    __shared__ int las;
    int cell = blockIdx.x;
    int tid = threadIdx.x;
    if (tid < KNB) nb[tid] = nbrs[cell * KNB + tid];
    if (tid == KNB) las = lasing[cell];
    __syncthreads();

    float2 raw = rot2[(size_t)cell * (HID / 2) + tid];
    __half2 sre = f2h2(raw.x), sim = f2h2(raw.y);
    float s0x = __low2float(sre), s1x = __high2float(sre);
    float s0y = __low2float(sim), s1y = __high2float(sim);
    float r0 = rsqrtf(s0x * s0x + s0y * s0y);
    float r1 = rsqrtf(s1x * s1x + s1y * s1y);

    __half2 are = __float2half2_rn(0.f), aim = __float2half2_rn(0.f);
#pragma unroll
    for (int t = 0; t < KNB; ++t) {
        float2 qraw = rot2[(size_t)nb[t] * (HID / 2) + tid];
        __half2 qre = f2h2(qraw.x), qim = f2h2(qraw.y);
        __half2 d  = __hfma2(sim, qim, __hmul2(sre, qre));   // s.q per channel
        __half2 qn = __hfma2(qim, qim, __hmul2(qre, qre));   // |q|^2
        __half2 t2 = __hmul2(d, h2rsqrt(qn));                // d * r_q
        are = __hfma2(t2, qre, are);
        aim = __hfma2(t2, qim, aim);
    }
    float ar0 = __low2float(are), ar1 = __high2float(are);
    float ai0 = __low2float(aim), ai1 = __high2float(aim);
    // new = 0.7*s + (0.3*0.1/15) * r_s * sum
    float k0 = 0.002f * r0, k1 = 0.002f * r1;
    float nr0 = 0.7f * s0x + k0 * ar0, ni0 = 0.7f * s0y + k0 * ai0;
    float nr1 = 0.7f * s1x + k1 * ar1, ni1 = 0.7f * s1y + k1 * ai1;
    nst2[(size_t)cell * (HID / 2) + tid] =
        make_float2(h22f(__floats2half2_rn(nr0, nr1)),
                    h22f(__floats2half2_rn(ni0, ni1)));
    if (las) {
        int c0 = tid << 1;
        float* em = emis + (size_t)(cell & (NCOPY - 1)) * 1024;
        atomicAdd(em + c0,     nr0); atomicAdd(em + 512 + c0,     ni0);
        atomicAdd(em + c0 + 1, nr1); atomicAdd(em + 512 + c0 + 1, ni1);
    }
}

// ---------------------------------------------------------------------------
// Kernel 3 (merged cav+pred): 64 blocks x 512 threads. Every block redundantly
// reduces lasing count + emission copies (20 MB total, L2-hot) -> cavity_new in
// LDS; block 0 also writes global cav[] (incl. OLD-cavity phase) for k_fin.
// Then 8 waves/block compute 8 rows of pred = out_real . dec_W[j] + db[j].
__global__ __launch_bounds__(512) void k_predcav(const float* __restrict__ emis,
                                                 const int* __restrict__ lasv,
                                                 const float* __restrict__ cavr,
                                                 const float* __restrict__ cavi,
                                                 const float* __restrict__ dW,
                                                 const float* __restrict__ db,
                                                 float* __restrict__ cav,
                                                 float* __restrict__ out) {
    __shared__ float sout[1024];                   // [re512 | im512] cavity_new
    __shared__ int cnt[8];
    __shared__ int snl;
    int c = threadIdx.x;
    int wid = c >> 6, lane = c & 63;

    const int4* l4 = (const int4*)lasv;
    int n = 0;
#pragma unroll
    for (int k = 0; k < N_CELLS / 4 / 512; ++k) {  // 8 iters of int4
        int4 v = l4[c + 512 * k];
        n += v.x + v.y + v.z + v.w;
    }
#pragma unroll
    for (int o = 32; o; o >>= 1) n += __shfl_xor(n, o, 64);
    if (lane == 0) cnt[wid] = n;
    __syncthreads();
    if (c == 0) { int t = 0; for (int k = 0; k < 8; ++k) t += cnt[k]; snl = t; }
    __syncthreads();
    int nl = snl;

    float er = 0.f, ei = 0.f;
#pragma unroll 8
    for (int k = 0; k < NCOPY; ++k) {
        er += emis[k * 1024 + c];
        ei += emis[k * 1024 + 512 + c];
    }
    float crv = cavr[c], civ = cavi[c];
    float nr, ni;
    if (nl > 0) {
        float inv = 1.f / (float)(nl > 1 ? nl : 1);
        nr = 0.8f * crv + 0.2f * er * inv;
        ni = 0.8f * civ + 0.2f * ei * inv;
    } else {
        nr = crv;
        ni = civ;
    }
    sout[c] = nr;
    sout[512 + c] = ni;
    if (blockIdx.x == 0) {
        cav[c] = nr;
        cav[512 + c] = ni;
        cav[1024 + c] = atan2f(civ, crv);          // old cavity phase
    }
    __syncthreads();

    // pred: wave w of this block handles row j
    int j = blockIdx.x * 8 + wid;
    const float4* w4 = (const float4*)(dW + (size_t)j * (2 * HID));
    const float4* o4 = (const float4*)sout;
    float acc = 0.f;
#pragma unroll
    for (int t = 0; t < 4; ++t) {
        float4 a = w4[lane + 64 * t];
        float4 bx = o4[lane + 64 * t];
        acc += a.x * bx.x + a.y * bx.y + a.z * bx.z + a.w * bx.w;
    }
#pragma unroll
    for (int o = 32; o; o >>= 1) acc += __shfl_xor(acc, o, 64);
    if (lane == 0) out[j] = acc + db[j];
}

// ---------------------------------------------------------------------------
// Kernel 4 (merged fin+var): phase-lock lasing cells, cavity feedback, row-max
// renorm, per-cell (sum_a, sum_a2) partial; LAST block reduces partials and
// writes tension. Block per cell, 256 threads, 2 channels/thread (planar).
__global__ __launch_bounds__(256) void k_fin(const float2* __restrict__ nst2,
                                             const int* __restrict__ lasing,
                                             const float* __restrict__ cav,
                                             float2* __restrict__ vpart,
                                             int* __restrict__ cnt,
                                             float* __restrict__ out) {
    __shared__ float sred[4];
    __shared__ float sbc;
    __shared__ float w1[4], w2[4];
    int cell = blockIdx.x;
    int t = threadIdx.x;
    int wid = t >> 6, lane = t & 63;
    int las = lasing[cell];
    int c0 = t << 1;

    float2 raw = nst2[(size_t)cell * (HID / 2) + t];
    __half2 reh = f2h2(raw.x), imh = f2h2(raw.y);
    float vx0 = __low2float(reh), vx1 = __high2float(reh);
    float vy0 = __low2float(imh), vy1 = __high2float(imh);
    if (las) {
        float r0 = sqrtf(vx0 * vx0 + vy0 * vy0);
        float r1 = sqrtf(vx1 * vx1 + vy1 * vy1);
        float l0 = 0.3f * cav[1024 + c0]     + 0.7f * atan2f(vy0, vx0);
        float l1 = 0.3f * cav[1024 + c0 + 1] + 0.7f * atan2f(vy1, vx1);
        float sn0, cs0, sn1, cs1;
        __sincosf(l0, &sn0, &cs0);
        __sincosf(l1, &sn1, &cs1);
        vx0 = r0 * cs0; vy0 = r0 * sn0;
        vx1 = r1 * cs1; vy1 = r1 * sn1;
    }
    vx0 += 0.05f * cav[c0];     vy0 += 0.05f * cav[512 + c0];
    vx1 += 0.05f * cav[c0 + 1]; vy1 += 0.05f * cav[512 + c0 + 1];
    float amp0 = sqrtf(vx0 * vx0 + vy0 * vy0);
    float amp1 = sqrtf(vx1 * vx1 + vy1 * vy1);

    // block max over 512 channels (4 waves)
    float m = fmaxf(amp0, amp1);
#pragma unroll
    for (int o = 32; o; o >>= 1) m = fmaxf(m, __shfl_xor(m, o, 64));
    if (lane == 0) sred[wid] = m;
    __syncthreads();
    if (t == 0)
        sbc = fmaxf(fmaxf(sred[0], sred[1]), fmaxf(sred[2], sred[3]));
    __syncthreads();
    float inv = 1.f / (sbc + 1e-8f);
    float a0 = amp0 * inv, a1 = amp1 * inv;

    float s1 = a0 + a1, s2 = a0 * a0 + a1 * a1;
#pragma unroll
    for (int o = 32; o; o >>= 1) { s1 += __shfl_xor(s1, o, 64); s2 += __shfl_xor(s2, o, 64); }
    if (lane == 0) { w1[wid] = s1; w2[wid] = s2; }
    __syncthreads();
    __shared__ int slast;
    if (t == 0) {
        vpart[cell] = make_float2(w1[0] + w1[1] + w1[2] + w1[3],
                                  w2[0] + w2[1] + w2[2] + w2[3]);
        __threadfence();
        int old = atomicAdd(cnt, 1);
        slast = (old == N_CELLS - 1) ? 1 : 0;
    }
    __syncthreads();
    if (slast) {
        // last block: reduce all per-cell partials, write tension
        __threadfence();
        double d1 = 0.0, d2 = 0.0;
#pragma unroll
        for (int k = 0; k < N_CELLS / 256; ++k) {  // 64 iters
            float2 p = vpart[t + 256 * k];
            d1 += (double)p.x;
            d2 += (double)p.y;
        }
#pragma unroll
        for (int o = 32; o; o >>= 1) { d1 += __shfl_xor(d1, o, 64); d2 += __shfl_xor(d2, o, 64); }
        __shared__ double l1[4], l2[4];
        if (lane == 0) { l1[wid] = d1; l2[wid] = d2; }
        __syncthreads();
        if (t == 0) {
            double t1 = l1[0] + l1[1] + l1[2] + l1[3];
            double t2 = l2[0] + l2[1] + l2[2] + l2[3];
            double nn = (double)N_CELLS * (double)HID;
            double mean = t1 / nn;
            out[IND] = (float)(t2 / nn - mean * mean);
        }
    }
}

// ---------------------------------------------------------------------------
extern "C" void kernel_launch(void* const* d_in, const int* in_sizes, int n_in,
                              void* d_out, int out_size, void* d_ws, size_t ws_size,
                              hipStream_t stream) {
    const float* x       = (const float*)d_in[0];
    const float* pump_W  = (const float*)d_in[1];
    const float* pump_b  = (const float*)d_in[2];
    const float* dec_W   = (const float*)d_in[3];
    const float* dec_b   = (const float*)d_in[4];
    const float* cs_re   = (const float*)d_in[5];
    const float* cs_im   = (const float*)d_in[6];
    const float* excited = (const float*)d_in[7];
    const float* pvel    = (const float*)d_in[8];
    const float* cav_re  = (const float*)d_in[9];
    const float* cav_im  = (const float*)d_in[10];
    const int*   nbrs    = (const int*)d_in[11];

    float* out = (float*)d_out;
    char* ws = (char*)d_ws;
    int*    cnt   = (int*)(ws + CNT_OFF);
    float*  emis  = (float*)(ws + EMIS_OFF);
    int*    lasv  = (int*)(ws + LAS_OFF);
    float*  cav   = (float*)(ws + CAV_OFF);
    float2* vpart = (float2*)(ws + VPART_OFF);
    float2* rot2  = (float2*)(ws + ROT_OFF);
    float2* nst2  = (float2*)(ws + NST_OFF);

    k_front<<<ROT_BLOCKS + PUMP_BLOCKS + ZERO_BLOCKS, 256, 0, stream>>>(
        cs_re, cs_im, pvel, (float4*)rot2, x, pump_W, pump_b, excited, lasv, emis, cnt);
    k_coup<<<N_CELLS, 256, 0, stream>>>(rot2, nbrs, lasv, nst2, emis);
    k_predcav<<<64, 512, 0, stream>>>(emis, lasv, cav_re, cav_im, dec_W, dec_b, cav, out);
    k_fin<<<N_CELLS, 256, 0, stream>>>(nst2, lasv, cav, vpart, cnt, out);
}

// Round 7
// 266.768 us; speedup vs baseline: 2.1331x; 2.1331x over previous
//
#include <hip/hip_runtime.h>
#include <hip/hip_fp16.h>
#include <math.h>

#define N_CELLS 16384
#define HID 512
#define IND 512
#define KNB 15
#define NCOPY 64

#define ROT_BLOCKS  8192    // N*H/4 elems / 256 threads
#define PUMP_BLOCKS 4096    // 4 cells per block (wave per cell)
#define ZERO_BLOCKS 64      // 64*256 float4 = 65536 floats (emis)

#define CPB 32                          // cells per k_finall cell-block
#define CELL_BLOCKS (N_CELLS / CPB)     // 512  -> only 512 counter atomics
#define PRED_BLOCKS 128                 // 4 pred rows per block (4 waves)

// ---- workspace layout (bytes) ----
#define CNT_OFF   0                                   // int: last-block counter
#define EMIS_OFF  128                                 // float[NCOPY][1024]: emission partials (re[512], im[512])
#define LAS_OFF   (EMIS_OFF + NCOPY*1024*4)           // int[N_CELLS]: lasing flags
#define VPART_OFF (LAS_OFF + N_CELLS*4)               // float2[CELL_BLOCKS]: per-block (sum_a, sum_a2)
#define ROT_OFF   (1<<20)                             // planar fp16: per row, 256 x {re-pair, im-pair}
#define NST_OFF   (ROT_OFF + (size_t)N_CELLS*HID*4)   // same layout, new_states

__device__ inline __half2 f2h2(float f) { union { float f; __half2 h; } u; u.f = f; return u.h; }
__device__ inline float   h22f(__half2 h) { union { float f; __half2 h; } u; u.h = h; return u.f; }

// ---------------------------------------------------------------------------
// Kernel 1 (fused front): phase rotation (planar fp16 out) + pump/lasing +
// emis zeroing + counter zeroing.
__global__ __launch_bounds__(256) void k_front(const float* __restrict__ cr,
                                               const float* __restrict__ ci,
                                               const float* __restrict__ pv,
                                               float4* __restrict__ rot,
                                               const float* __restrict__ x,
                                               const float* __restrict__ pW,
                                               const float* __restrict__ pb,
                                               const float* __restrict__ excited,
                                               int* __restrict__ lasing,
                                               float* __restrict__ emis,
                                               int* __restrict__ cnt) {
    int b = blockIdx.x;
    int tid = threadIdx.x;
    if (b < ROT_BLOCKS) {
        // ---- rotate by exp(i*0.1*pv), 4 channels/thread, planar pack ----
        int i = b * 256 + tid;
        const float4* cr4 = (const float4*)cr;
        const float4* ci4 = (const float4*)ci;
        const float4* pv4 = (const float4*)pv;
        float4 a = cr4[i], bb = ci4[i], t = pv4[i];
        float s0, c0, s1, c1, s2, c2, s3, c3;
        __sincosf(0.1f * t.x, &s0, &c0);
        __sincosf(0.1f * t.y, &s1, &c1);
        __sincosf(0.1f * t.z, &s2, &c2);
        __sincosf(0.1f * t.w, &s3, &c3);
        float re0 = a.x * c0 - bb.x * s0, im0 = a.x * s0 + bb.x * c0;
        float re1 = a.y * c1 - bb.y * s1, im1 = a.y * s1 + bb.y * c1;
        float re2 = a.z * c2 - bb.z * s2, im2 = a.z * s2 + bb.z * c2;
        float re3 = a.w * c3 - bb.w * s3, im3 = a.w * s3 + bb.w * c3;
        // planar: {re01, im01, re23, im23}
        rot[i] = make_float4(h22f(__floats2half2_rn(re0, re1)),
                             h22f(__floats2half2_rn(im0, im1)),
                             h22f(__floats2half2_rn(re2, re3)),
                             h22f(__floats2half2_rn(im2, im3)));
    } else if (b < ROT_BLOCKS + PUMP_BLOCKS) {
        // ---- pump = sigmoid(x . pump_W[cell] + pb); lasing flag. Wave/cell ----
        int gtid = (b - ROT_BLOCKS) * 256 + tid;
        int cell = gtid >> 6;
        int lane = gtid & 63;
        const float4* w4 = (const float4*)(pW + (size_t)cell * IND);
        const float4* x4 = (const float4*)x;
        float acc = 0.f;
#pragma unroll
        for (int t = 0; t < (IND / 4) / 64; ++t) {   // 2 iters
            float4 a = w4[lane + 64 * t];
            float4 bx = x4[lane + 64 * t];
            acc += a.x * bx.x + a.y * bx.y + a.z * bx.z + a.w * bx.w;
        }
#pragma unroll
        for (int o = 32; o; o >>= 1) acc += __shfl_xor(acc, o, 64);
        if (lane == 0) {
            float p = 1.f / (1.f + expf(-(acc + pb[cell])));
            float e = excited[cell] * 0.95f + p * 0.05f;
            e = fminf(fmaxf(e, 0.f), 1.f);
            lasing[cell] = (e > 0.5f) ? 1 : 0;
        }
    } else {
        // ---- zero emission accumulators + last-block counter ----
        int zb = b - ROT_BLOCKS - PUMP_BLOCKS;
        int idx = zb * 256 + tid;
        ((float4*)emis)[idx] = make_float4(0.f, 0.f, 0.f, 0.f);
        if (zb == 0 && tid == 0) *cnt = 0;
    }
}

// ---------------------------------------------------------------------------
// Kernel 2: neighbor coupling, planar fp16, packed-half inner loop.
// Block = 1 cell, natural dispatch order (round-3 lesson: do NOT swizzle).
// 256 threads, 2 channels/thread; per gather: one 8B load -> (re-pair, im-pair).
__global__ __launch_bounds__(256) void k_coup(const float2* __restrict__ rot2,
                                              const int* __restrict__ nbrs,
                                              const int* __restrict__ lasing,
                                              float2* __restrict__ nst2,
                                              float* __restrict__ emis) {
    __shared__ int nb[KNB];
    __shared__ int las;
    int cell = blockIdx.x;
    int tid = threadIdx.x;
    if (tid < KNB) nb[tid] = nbrs[cell * KNB + tid];
    if (tid == KNB) las = lasing[cell];
    __syncthreads();

    float2 raw = rot2[(size_t)cell * (HID / 2) + tid];
    __half2 sre = f2h2(raw.x), sim = f2h2(raw.y);
    float s0x = __low2float(sre), s1x = __high2float(sre);
    float s0y = __low2float(sim), s1y = __high2float(sim);
    float r0 = rsqrtf(s0x * s0x + s0y * s0y);
    float r1 = rsqrtf(s1x * s1x + s1y * s1y);

    __half2 are = __float2half2_rn(0.f), aim = __float2half2_rn(0.f);
#pragma unroll
    for (int t = 0; t < KNB; ++t) {
        float2 qraw = rot2[(size_t)nb[t] * (HID / 2) + tid];
        __half2 qre = f2h2(qraw.x), qim = f2h2(qraw.y);
        __half2 d  = __hfma2(sim, qim, __hmul2(sre, qre));   // s.q per channel
        __half2 qn = __hfma2(qim, qim, __hmul2(qre, qre));   // |q|^2
        __half2 t2 = __hmul2(d, h2rsqrt(qn));                // d * r_q
        are = __hfma2(t2, qre, are);
        aim = __hfma2(t2, qim, aim);
    }
    float ar0 = __low2float(are), ar1 = __high2float(are);
    float ai0 = __low2float(aim), ai1 = __high2float(aim);
    // new = 0.7*s + (0.3*0.1/15) * r_s * sum
    float k0 = 0.002f * r0, k1 = 0.002f * r1;
    float nr0 = 0.7f * s0x + k0 * ar0, ni0 = 0.7f * s0y + k0 * ai0;
    float nr1 = 0.7f * s1x + k1 * ar1, ni1 = 0.7f * s1y + k1 * ai1;
    nst2[(size_t)cell * (HID / 2) + tid] =
        make_float2(h22f(__floats2half2_rn(nr0, nr1)),
                    h22f(__floats2half2_rn(ni0, ni1)));
    if (las) {
        int c0 = tid << 1;
        float* em = emis + (size_t)(cell & (NCOPY - 1)) * 1024;
        atomicAdd(em + c0,     nr0); atomicAdd(em + 512 + c0,     ni0);
        atomicAdd(em + c0 + 1, nr1); atomicAdd(em + 512 + c0 + 1, ni1);
    }
}

// ---------------------------------------------------------------------------
// Kernel 3 (cav + pred + fin + var in ONE dispatch). 640 blocks x 256 threads.
// EVERY block redundantly computes cavity_new + old-cavity phase from
// emis/lasv/cav inputs (320 KB L2-hot per block).  Blocks 0..511: 32 cells
// each (phase-lock, feedback, renorm, variance partial); ONLY 512 counter
// atomics -> no serialization.  Blocks 512..639: 4 pred GEMV rows each.
__global__ __launch_bounds__(256) void k_finall(const float2* __restrict__ nst2,
                                                const int* __restrict__ lasv,
                                                const float* __restrict__ emis,
                                                const float* __restrict__ cavr,
                                                const float* __restrict__ cavi,
                                                const float* __restrict__ dW,
                                                const float* __restrict__ db,
                                                float2* __restrict__ vpart,
                                                int* __restrict__ cnt,
                                                float* __restrict__ out) {
    __shared__ float sout[1024];                   // cavity_new [re512 | im512]
    __shared__ float sphase[512];                  // OLD cavity phase
    __shared__ int   ic[4];
    __shared__ int   snl;
    __shared__ float sred[4];
    __shared__ float sbc;
    __shared__ float w1[4], w2[4];
    __shared__ int   slast;

    int t = threadIdx.x;
    int wid = t >> 6, lane = t & 63;

    // ---- cavity prologue (every block) ----
    const int4* l4 = (const int4*)lasv;
    int n = 0;
#pragma unroll
    for (int k = 0; k < N_CELLS / 4 / 256; ++k) {  // 16 iters of int4
        int4 v = l4[t + 256 * k];
        n += v.x + v.y + v.z + v.w;
    }
#pragma unroll
    for (int o = 32; o; o >>= 1) n += __shfl_xor(n, o, 64);
    if (lane == 0) ic[wid] = n;

    float4 acc = make_float4(0.f, 0.f, 0.f, 0.f);  // emis channels 4t..4t+3
    const float4* e4 = (const float4*)emis;
#pragma unroll 8
    for (int k = 0; k < NCOPY; ++k) {
        float4 v = e4[k * 256 + t];
        acc.x += v.x; acc.y += v.y; acc.z += v.z; acc.w += v.w;
    }
    __syncthreads();
    if (t == 0) snl = ic[0] + ic[1] + ic[2] + ic[3];
    __syncthreads();
    int nl = snl;

    const float4* cr4 = (const float4*)cavr;       // 128 groups
    const float4* ci4 = (const float4*)cavi;
    float4 cv = (t < 128) ? cr4[t] : ci4[t - 128];
    float4 nv;
    if (nl > 0) {
        float inv = 0.2f / (float)(nl > 1 ? nl : 1);
        nv = make_float4(0.8f * cv.x + acc.x * inv, 0.8f * cv.y + acc.y * inv,
                         0.8f * cv.z + acc.z * inv, 0.8f * cv.w + acc.w * inv);
    } else {
        nv = cv;
    }
    ((float4*)sout)[t] = nv;
    if (t < 128) {                                 // old cavity phase, 4 ch/thread
        float4 cr = cr4[t], ci = ci4[t];
        sphase[4 * t]     = atan2f(ci.x, cr.x);
        sphase[4 * t + 1] = atan2f(ci.y, cr.y);
        sphase[4 * t + 2] = atan2f(ci.z, cr.z);
        sphase[4 * t + 3] = atan2f(ci.w, cr.w);
    }
    __syncthreads();

    int b = blockIdx.x;
    if (b < CELL_BLOCKS) {
        // ---- cell role: 32 cells, 2 channels/thread (planar fp16) ----
        int c0 = t << 1;
        float fcr0 = 0.05f * sout[c0],       fcr1 = 0.05f * sout[c0 + 1];
        float fci0 = 0.05f * sout[512 + c0], fci1 = 0.05f * sout[512 + c0 + 1];
        float ph0 = sphase[c0], ph1 = sphase[c0 + 1];
        float s1 = 0.f, s2 = 0.f;
        for (int i = 0; i < CPB; ++i) {
            int cell = b * CPB + i;
            int las = lasv[cell];
            float2 raw = nst2[(size_t)cell * (HID / 2) + t];
            __half2 reh = f2h2(raw.x), imh = f2h2(raw.y);
            float vx0 = __low2float(reh), vx1 = __high2float(reh);
            float vy0 = __low2float(imh), vy1 = __high2float(imh);
            if (las) {
                float r0 = sqrtf(vx0 * vx0 + vy0 * vy0);
                float r1 = sqrtf(vx1 * vx1 + vy1 * vy1);
                float l0 = 0.3f * ph0 + 0.7f * atan2f(vy0, vx0);
                float l1 = 0.3f * ph1 + 0.7f * atan2f(vy1, vx1);
                float sn0, cs0, sn1, cs1;
                __sincosf(l0, &sn0, &cs0);
                __sincosf(l1, &sn1, &cs1);
                vx0 = r0 * cs0; vy0 = r0 * sn0;
                vx1 = r1 * cs1; vy1 = r1 * sn1;
            }
            vx0 += fcr0; vy0 += fci0;
            vx1 += fcr1; vy1 += fci1;
            float amp0 = sqrtf(vx0 * vx0 + vy0 * vy0);
            float amp1 = sqrtf(vx1 * vx1 + vy1 * vy1);
            // per-cell max
            float m = fmaxf(amp0, amp1);
#pragma unroll
            for (int o = 32; o; o >>= 1) m = fmaxf(m, __shfl_xor(m, o, 64));
            if (lane == 0) sred[wid] = m;
            __syncthreads();
            if (t == 0)
                sbc = fmaxf(fmaxf(sred[0], sred[1]), fmaxf(sred[2], sred[3]));
            __syncthreads();
            float inv = 1.f / (sbc + 1e-8f);
            float a0 = amp0 * inv, a1 = amp1 * inv;
            s1 += a0 + a1;
            s2 += a0 * a0 + a1 * a1;
        }
        // block partial
#pragma unroll
        for (int o = 32; o; o >>= 1) { s1 += __shfl_xor(s1, o, 64); s2 += __shfl_xor(s2, o, 64); }
        if (lane == 0) { w1[wid] = s1; w2[wid] = s2; }
        __syncthreads();
        if (t == 0) {
            vpart[b] = make_float2(w1[0] + w1[1] + w1[2] + w1[3],
                                   w2[0] + w2[1] + w2[2] + w2[3]);
            __threadfence();
            int old = atomicAdd(cnt, 1);           // only 512 of these
            slast = (old == CELL_BLOCKS - 1) ? 1 : 0;
        }
        __syncthreads();
        if (slast) {
            __threadfence();
            double d1 = (double)vpart[t].x + (double)vpart[t + 256].x;
            double d2 = (double)vpart[t].y + (double)vpart[t + 256].y;
#pragma unroll
            for (int o = 32; o; o >>= 1) { d1 += __shfl_xor(d1, o, 64); d2 += __shfl_xor(d2, o, 64); }
            __shared__ double l1s[4], l2s[4];
            if (lane == 0) { l1s[wid] = d1; l2s[wid] = d2; }
            __syncthreads();
            if (t == 0) {
                double t1 = l1s[0] + l1s[1] + l1s[2] + l1s[3];
                double t2 = l2s[0] + l2s[1] + l2s[2] + l2s[3];
                double nn = (double)N_CELLS * (double)HID;
                double mean = t1 / nn;
                out[IND] = (float)(t2 / nn - mean * mean);
            }
        }
    } else {
        // ---- pred role: wave wid computes row j ----
        int j = (b - CELL_BLOCKS) * 4 + wid;
        const float4* w4 = (const float4*)(dW + (size_t)j * (2 * HID));
        const float4* o4 = (const float4*)sout;
        float a2 = 0.f;
#pragma unroll
        for (int tt = 0; tt < 4; ++tt) {
            float4 a = w4[lane + 64 * tt];
            float4 bx = o4[lane + 64 * tt];
            a2 += a.x * bx.x + a.y * bx.y + a.z * bx.z + a.w * bx.w;
        }
#pragma unroll
        for (int o = 32; o; o >>= 1) a2 += __shfl_xor(a2, o, 64);
        if (lane == 0) out[j] = a2 + db[j];
    }
}

// ---------------------------------------------------------------------------
extern "C" void kernel_launch(void* const* d_in, const int* in_sizes, int n_in,
                              void* d_out, int out_size, void* d_ws, size_t ws_size,
                              hipStream_t stream) {
    const float* x       = (const float*)d_in[0];
    const float* pump_W  = (const float*)d_in[1];
    const float* pump_b  = (const float*)d_in[2];
    const float* dec_W   = (const float*)d_in[3];
    const float* dec_b   = (const float*)d_in[4];
    const float* cs_re   = (const float*)d_in[5];
    const float* cs_im   = (const float*)d_in[6];
    const float* excited = (const float*)d_in[7];
    const float* pvel    = (const float*)d_in[8];
    const float* cav_re  = (const float*)d_in[9];
    const float* cav_im  = (const float*)d_in[10];
    const int*   nbrs    = (const int*)d_in[11];

    float* out = (float*)d_out;
    char* ws = (char*)d_ws;
    int*    cnt   = (int*)(ws + CNT_OFF);
    float*  emis  = (float*)(ws + EMIS_OFF);
    int*    lasv  = (int*)(ws + LAS_OFF);
    float2* vpart = (float2*)(ws + VPART_OFF);
    float2* rot2  = (float2*)(ws + ROT_OFF);
    float2* nst2  = (float2*)(ws + NST_OFF);

    k_front<<<ROT_BLOCKS + PUMP_BLOCKS + ZERO_BLOCKS, 256, 0, stream>>>(
        cs_re, cs_im, pvel, (float4*)rot2, x, pump_W, pump_b, excited, lasv, emis, cnt);
    k_coup<<<N_CELLS, 256, 0, stream>>>(rot2, nbrs, lasv, nst2, emis);
    k_finall<<<CELL_BLOCKS + PRED_BLOCKS, 256, 0, stream>>>(
        nst2, lasv, emis, cav_re, cav_im, dec_W, dec_b, vpart, cnt, out);
}

// Round 8
// 252.991 us; speedup vs baseline: 2.2493x; 1.0545x over previous
//
#include <hip/hip_runtime.h>
#include <hip/hip_fp16.h>
#include <math.h>

#define N_CELLS 16384
#define HID 512
#define IND 512
#define KNB 15
#define NCOPY 64

#define ROT_BLOCKS  8192    // N*H/4 elems / 256 threads
#define PUMP_BLOCKS 4096    // 4 cells per block (wave per cell)
#define ZERO_BLOCKS 64      // 64*256 float4 = 65536 floats (emis)

#define CPB 32                          // cells per k_finall cell-block (8/wave)
#define CELL_BLOCKS (N_CELLS / CPB)     // 512  -> only 512 counter atomics
#define PRED_BLOCKS 128                 // 4 pred rows per block (4 waves)

// ---- workspace layout (bytes) ----
#define CNT_OFF   0                                   // int: last-block counter
#define EMIS_OFF  128                                 // float[NCOPY][1024]: emission partials (re[512], im[512])
#define LAS_OFF   (EMIS_OFF + NCOPY*1024*4)           // int[N_CELLS]: lasing flags
#define VPART_OFF (LAS_OFF + N_CELLS*4)               // float2[CELL_BLOCKS]: per-block (sum_a, sum_a2)
#define ROT_OFF   (1<<20)                             // planar fp16 y = s/sqrt(|s|): per row, 256 x {re-pair, im-pair}
#define NST_OFF   (ROT_OFF + (size_t)N_CELLS*HID*4)   // same layout, new_states (raw value, fp16)

__device__ inline __half2 f2h2(float f) { union { float f; __half2 h; } u; u.f = f; return u.h; }
__device__ inline float   h22f(__half2 h) { union { float f; __half2 h; } u; u.h = h; return u.f; }

// ---------------------------------------------------------------------------
// Kernel 1 (fused front): phase rotation -> y = s/sqrt(|s|) (planar fp16) +
// pump/lasing + emis zeroing + counter zeroing.
__global__ __launch_bounds__(256) void k_front(const float* __restrict__ cr,
                                               const float* __restrict__ ci,
                                               const float* __restrict__ pv,
                                               float4* __restrict__ yout,
                                               const float* __restrict__ x,
                                               const float* __restrict__ pW,
                                               const float* __restrict__ pb,
                                               const float* __restrict__ excited,
                                               int* __restrict__ lasing,
                                               float* __restrict__ emis,
                                               int* __restrict__ cnt) {
    int b = blockIdx.x;
    int tid = threadIdx.x;
    if (b < ROT_BLOCKS) {
        // ---- rotate by exp(i*0.1*pv); scale by |s|^{-1/2}; planar pack ----
        int i = b * 256 + tid;
        const float4* cr4 = (const float4*)cr;
        const float4* ci4 = (const float4*)ci;
        const float4* pv4 = (const float4*)pv;
        float4 a = cr4[i], bb = ci4[i], t = pv4[i];
        // magnitude is rotation-invariant: compute from inputs (hides latency)
        float sc0 = rsqrtf(sqrtf(a.x * a.x + bb.x * bb.x));   // |s|^{-1/2}
        float sc1 = rsqrtf(sqrtf(a.y * a.y + bb.y * bb.y));
        float sc2 = rsqrtf(sqrtf(a.z * a.z + bb.z * bb.z));
        float sc3 = rsqrtf(sqrtf(a.w * a.w + bb.w * bb.w));
        float s0, c0, s1, c1, s2, c2, s3, c3;
        __sincosf(0.1f * t.x, &s0, &c0);
        __sincosf(0.1f * t.y, &s1, &c1);
        __sincosf(0.1f * t.z, &s2, &c2);
        __sincosf(0.1f * t.w, &s3, &c3);
        float re0 = (a.x * c0 - bb.x * s0) * sc0, im0 = (a.x * s0 + bb.x * c0) * sc0;
        float re1 = (a.y * c1 - bb.y * s1) * sc1, im1 = (a.y * s1 + bb.y * c1) * sc1;
        float re2 = (a.z * c2 - bb.z * s2) * sc2, im2 = (a.z * s2 + bb.z * c2) * sc2;
        float re3 = (a.w * c3 - bb.w * s3) * sc3, im3 = (a.w * s3 + bb.w * c3) * sc3;
        // planar: {re01, im01, re23, im23}
        yout[i] = make_float4(h22f(__floats2half2_rn(re0, re1)),
                              h22f(__floats2half2_rn(im0, im1)),
                              h22f(__floats2half2_rn(re2, re3)),
                              h22f(__floats2half2_rn(im2, im3)));
    } else if (b < ROT_BLOCKS + PUMP_BLOCKS) {
        // ---- pump = sigmoid(x . pump_W[cell] + pb); lasing flag. Wave/cell ----
        int gtid = (b - ROT_BLOCKS) * 256 + tid;
        int cell = gtid >> 6;
        int lane = gtid & 63;
        const float4* w4 = (const float4*)(pW + (size_t)cell * IND);
        const float4* x4 = (const float4*)x;
        float acc = 0.f;
#pragma unroll
        for (int t = 0; t < (IND / 4) / 64; ++t) {   // 2 iters
            float4 a = w4[lane + 64 * t];
            float4 bx = x4[lane + 64 * t];
            acc += a.x * bx.x + a.y * bx.y + a.z * bx.z + a.w * bx.w;
        }
#pragma unroll
        for (int o = 32; o; o >>= 1) acc += __shfl_xor(acc, o, 64);
        if (lane == 0) {
            float p = 1.f / (1.f + expf(-(acc + pb[cell])));
            float e = excited[cell] * 0.95f + p * 0.05f;
            e = fminf(fmaxf(e, 0.f), 1.f);
            lasing[cell] = (e > 0.5f) ? 1 : 0;
        }
    } else {
        // ---- zero emission accumulators + last-block counter ----
        int zb = b - ROT_BLOCKS - PUMP_BLOCKS;
        int idx = zb * 256 + tid;
        ((float4*)emis)[idx] = make_float4(0.f, 0.f, 0.f, 0.f);
        if (zb == 0 && tid == 0) *cnt = 0;
    }
}

// ---------------------------------------------------------------------------
// Kernel 2: neighbor coupling on y = s/sqrt(|s|):
//   cos(ang_s-ang_t)*q_t = |s|^{-1/2} * (y_s . y_t) * y_t    (exact identity)
// Inner loop per neighbor per 2 channels: ONE 8B load + 4 packed-half ops.
// No per-neighbor rsqrt, no extra traffic. Block = 1 cell, natural order
// (round-3 lesson: do NOT swizzle). 256 threads, 2 channels/thread.
__global__ __launch_bounds__(256) void k_coup(const float2* __restrict__ y2,
                                              const int* __restrict__ nbrs,
                                              const int* __restrict__ lasing,
                                              float2* __restrict__ nst2,
                                              float* __restrict__ emis) {
    __shared__ int nb[KNB];
    __shared__ int las;
    int cell = blockIdx.x;
    int tid = threadIdx.x;
    if (tid < KNB) nb[tid] = nbrs[cell * KNB + tid];
    if (tid == KNB) las = lasing[cell];
    __syncthreads();

    float2 raw = y2[(size_t)cell * (HID / 2) + tid];
    __half2 yre = f2h2(raw.x), yim = f2h2(raw.y);
    float y0x = __low2float(yre), y1x = __high2float(yre);
    float y0y = __low2float(yim), y1y = __high2float(yim);
    float a0 = y0x * y0x + y0y * y0y;              // |y|^2 = |s|
    float a1 = y1x * y1x + y1y * y1y;

    __half2 are = __float2half2_rn(0.f), aim = __float2half2_rn(0.f);
#pragma unroll
    for (int t = 0; t < KNB; ++t) {
        float2 q = y2[(size_t)nb[t] * (HID / 2) + tid];
        __half2 qre = f2h2(q.x), qim = f2h2(q.y);
        __half2 d = __hfma2(yim, qim, __hmul2(yre, qre));    // y_s . y_t
        are = __hfma2(d, qre, are);
        aim = __hfma2(d, qim, aim);
    }
    float rs0 = rsqrtf(a0), rs1 = rsqrtf(a1);      // |s|^{-1/2}
    float sq0 = a0 * rs0, sq1 = a1 * rs1;          // |s|^{+1/2}
    // new = 0.7*s + 0.002 * |s|^{-1/2} * acc ;  s = |s|^{1/2} * y
    float c0 = 0.7f * sq0, c1 = 0.7f * sq1;
    float k0 = 0.002f * rs0, k1 = 0.002f * rs1;
    float nr0 = c0 * y0x + k0 * __low2float(are);
    float ni0 = c0 * y0y + k0 * __low2float(aim);
    float nr1 = c1 * y1x + k1 * __high2float(are);
    float ni1 = c1 * y1y + k1 * __high2float(aim);
    nst2[(size_t)cell * (HID / 2) + tid] =
        make_float2(h22f(__floats2half2_rn(nr0, nr1)),
                    h22f(__floats2half2_rn(ni0, ni1)));
    if (las) {
        int c0i = tid << 1;
        float* em = emis + (size_t)(cell & (NCOPY - 1)) * 1024;
        atomicAdd(em + c0i,     nr0); atomicAdd(em + 512 + c0i,     ni0);
        atomicAdd(em + c0i + 1, nr1); atomicAdd(em + 512 + c0i + 1, ni1);
    }
}

// ---------------------------------------------------------------------------
// process 2 channels of k_finall cell role (fp16 pair -> amps)
__device__ inline void chan2(float reh_f, float imh_f, int lasc,
                             float cr0, float cr1, float ci0, float ci1,
                             float p0, float p1, float& amp0, float& amp1) {
    __half2 reh = f2h2(reh_f), imh = f2h2(imh_f);
    float vx0 = __low2float(reh), vx1 = __high2float(reh);
    float vy0 = __low2float(imh), vy1 = __high2float(imh);
    if (lasc) {
        float r0 = sqrtf(vx0 * vx0 + vy0 * vy0);
        float r1 = sqrtf(vx1 * vx1 + vy1 * vy1);
        float l0 = 0.3f * p0 + 0.7f * atan2f(vy0, vx0);
        float l1 = 0.3f * p1 + 0.7f * atan2f(vy1, vx1);
        float sn0, cs0, sn1, cs1;
        __sincosf(l0, &sn0, &cs0);
        __sincosf(l1, &sn1, &cs1);
        vx0 = r0 * cs0; vy0 = r0 * sn0;
        vx1 = r1 * cs1; vy1 = r1 * sn1;
    }
    vx0 += 0.05f * cr0; vy0 += 0.05f * ci0;
    vx1 += 0.05f * cr1; vy1 += 0.05f * ci1;
    amp0 = sqrtf(vx0 * vx0 + vy0 * vy0);
    amp1 = sqrtf(vx1 * vx1 + vy1 * vy1);
}

// ---------------------------------------------------------------------------
// Kernel 3 (cav + pred + fin + var in ONE dispatch). 640 blocks x 256 threads.
// EVERY block redundantly computes cavity_new + old-cavity phase (L2-hot).
// Blocks 0..511: WAVE-PER-CELL (8 cells/wave, lane = 8 channels, per-lane cav
// constants preloaded) -> no __syncthreads in the cell loop; 512 counter
// atomics only. Blocks 512..639: 4 pred GEMV rows each.
__global__ __launch_bounds__(256) void k_finall(const float2* __restrict__ nst2,
                                                const int* __restrict__ lasv,
                                                const float* __restrict__ emis,
                                                const float* __restrict__ cavr,
                                                const float* __restrict__ cavi,
                                                const float* __restrict__ dW,
                                                const float* __restrict__ db,
                                                float2* __restrict__ vpart,
                                                int* __restrict__ cnt,
                                                float* __restrict__ out) {
    __shared__ float sout[1024];                   // cavity_new [re512 | im512]
    __shared__ float sphase[512];                  // OLD cavity phase
    __shared__ int   ic[4];
    __shared__ int   snl;
    __shared__ float w1[4], w2[4];
    __shared__ int   slast;

    int t = threadIdx.x;
    int wid = t >> 6, lane = t & 63;

    // ---- cavity prologue (every block) ----
    const int4* l4 = (const int4*)lasv;
    int n = 0;
#pragma unroll
    for (int k = 0; k < N_CELLS / 4 / 256; ++k) {  // 16 iters of int4
        int4 v = l4[t + 256 * k];
        n += v.x + v.y + v.z + v.w;
    }
#pragma unroll
    for (int o = 32; o; o >>= 1) n += __shfl_xor(n, o, 64);
    if (lane == 0) ic[wid] = n;

    float4 acc = make_float4(0.f, 0.f, 0.f, 0.f);  // emis channels 4t..4t+3
    const float4* e4 = (const float4*)emis;
#pragma unroll 8
    for (int k = 0; k < NCOPY; ++k) {
        float4 v = e4[k * 256 + t];
        acc.x += v.x; acc.y += v.y; acc.z += v.z; acc.w += v.w;
    }
    __syncthreads();
    if (t == 0) snl = ic[0] + ic[1] + ic[2] + ic[3];
    __syncthreads();
    int nl = snl;

    const float4* cr4 = (const float4*)cavr;       // 128 groups
    const float4* ci4 = (const float4*)cavi;
    float4 cv = (t < 128) ? cr4[t] : ci4[t - 128];
    float4 nv;
    if (nl > 0) {
        float inv = 0.2f / (float)(nl > 1 ? nl : 1);
        nv = make_float4(0.8f * cv.x + acc.x * inv, 0.8f * cv.y + acc.y * inv,
                         0.8f * cv.z + acc.z * inv, 0.8f * cv.w + acc.w * inv);
    } else {
        nv = cv;
    }
    ((float4*)sout)[t] = nv;
    if (t < 128) {                                 // old cavity phase, 4 ch/thread
        float4 cr = cr4[t], ci = ci4[t];
        sphase[4 * t]     = atan2f(ci.x, cr.x);
        sphase[4 * t + 1] = atan2f(ci.y, cr.y);
        sphase[4 * t + 2] = atan2f(ci.z, cr.z);
        sphase[4 * t + 3] = atan2f(ci.w, cr.w);
    }
    __syncthreads();

    int b = blockIdx.x;
    if (b < CELL_BLOCKS) {
        // ---- wave-per-cell: lane owns ch {4l..4l+3, 256+4l..256+4l+3} ----
        float4 cA = ((float4*)sout)[lane];         // cav re, low half
        float4 cB = ((float4*)sout)[lane + 64];    // cav re, high half
        float4 dA = ((float4*)sout)[128 + lane];   // cav im, low half
        float4 dB = ((float4*)sout)[128 + 64 + lane];
        float4 pA = ((float4*)sphase)[lane];
        float4 pB = ((float4*)sphase)[lane + 64];
        float s1 = 0.f, s2 = 0.f;
#pragma unroll 2
        for (int i = 0; i < CPB / 4; ++i) {        // 8 cells per wave
            int cell = b * CPB + wid * (CPB / 4) + i;
            int lasc = lasv[cell];
            const float4* nrow = (const float4*)nst2 + (size_t)cell * 128;
            float4 A = nrow[lane], B = nrow[lane + 64];
            float m0, m1, m2, m3, m4, m5, m6, m7;
            chan2(A.x, A.y, lasc, cA.x, cA.y, dA.x, dA.y, pA.x, pA.y, m0, m1);
            chan2(A.z, A.w, lasc, cA.z, cA.w, dA.z, dA.w, pA.z, pA.w, m2, m3);
            chan2(B.x, B.y, lasc, cB.x, cB.y, dB.x, dB.y, pB.x, pB.y, m4, m5);
            chan2(B.z, B.w, lasc, cB.z, cB.w, dB.z, dB.w, pB.z, pB.w, m6, m7);
            float mx = fmaxf(fmaxf(fmaxf(m0, m1), fmaxf(m2, m3)),
                             fmaxf(fmaxf(m4, m5), fmaxf(m6, m7)));
#pragma unroll
            for (int o = 32; o; o >>= 1) mx = fmaxf(mx, __shfl_xor(mx, o, 64));
            float inv = 1.f / (mx + 1e-8f);
            float a0 = m0 * inv, a1 = m1 * inv, a2 = m2 * inv, a3 = m3 * inv;
            float a4 = m4 * inv, a5 = m5 * inv, a6 = m6 * inv, a7 = m7 * inv;
            s1 += (a0 + a1) + (a2 + a3) + (a4 + a5) + (a6 + a7);
            s2 += (a0 * a0 + a1 * a1) + (a2 * a2 + a3 * a3)
                + (a4 * a4 + a5 * a5) + (a6 * a6 + a7 * a7);
        }
#pragma unroll
        for (int o = 32; o; o >>= 1) { s1 += __shfl_xor(s1, o, 64); s2 += __shfl_xor(s2, o, 64); }
        if (lane == 0) { w1[wid] = s1; w2[wid] = s2; }
        __syncthreads();
        if (t == 0) {
            vpart[b] = make_float2(w1[0] + w1[1] + w1[2] + w1[3],
                                   w2[0] + w2[1] + w2[2] + w2[3]);
            __threadfence();
            int old = atomicAdd(cnt, 1);           // only 512 of these
            slast = (old == CELL_BLOCKS - 1) ? 1 : 0;
        }
        __syncthreads();
        if (slast) {
            __threadfence();
            double d1 = (double)vpart[t].x + (double)vpart[t + 256].x;
            double d2 = (double)vpart[t].y + (double)vpart[t + 256].y;
#pragma unroll
            for (int o = 32; o; o >>= 1) { d1 += __shfl_xor(d1, o, 64); d2 += __shfl_xor(d2, o, 64); }
            __shared__ double l1s[4], l2s[4];
            if (lane == 0) { l1s[wid] = d1; l2s[wid] = d2; }
            __syncthreads();
            if (t == 0) {
                double t1 = l1s[0] + l1s[1] + l1s[2] + l1s[3];
                double t2 = l2s[0] + l2s[1] + l2s[2] + l2s[3];
                double nn = (double)N_CELLS * (double)HID;
                double mean = t1 / nn;
                out[IND] = (float)(t2 / nn - mean * mean);
            }
        }
    } else {
        // ---- pred role: wave wid computes row j ----
        int j = (b - CELL_BLOCKS) * 4 + wid;
        const float4* w4 = (const float4*)(dW + (size_t)j * (2 * HID));
        const float4* o4 = (const float4*)sout;
        float a2 = 0.f;
#pragma unroll
        for (int tt = 0; tt < 4; ++tt) {
            float4 a = w4[lane + 64 * tt];
            float4 bx = o4[lane + 64 * tt];
            a2 += a.x * bx.x + a.y * bx.y + a.z * bx.z + a.w * bx.w;
        }
#pragma unroll
        for (int o = 32; o; o >>= 1) a2 += __shfl_xor(a2, o, 64);
        if (lane == 0) out[j] = a2 + db[j];
    }
}

// ---------------------------------------------------------------------------
extern "C" void kernel_launch(void* const* d_in, const int* in_sizes, int n_in,
                              void* d_out, int out_size, void* d_ws, size_t ws_size,
                              hipStream_t stream) {
    const float* x       = (const float*)d_in[0];
    const float* pump_W  = (const float*)d_in[1];
    const float* pump_b  = (const float*)d_in[2];
    const float* dec_W   = (const float*)d_in[3];
    const float* dec_b   = (const float*)d_in[4];
    const float* cs_re   = (const float*)d_in[5];
    const float* cs_im   = (const float*)d_in[6];
    const float* excited = (const float*)d_in[7];
    const float* pvel    = (const float*)d_in[8];
    const float* cav_re  = (const float*)d_in[9];
    const float* cav_im  = (const float*)d_in[10];
    const int*   nbrs    = (const int*)d_in[11];

    float* out = (float*)d_out;
    char* ws = (char*)d_ws;
    int*    cnt   = (int*)(ws + CNT_OFF);
    float*  emis  = (float*)(ws + EMIS_OFF);
    int*    lasv  = (int*)(ws + LAS_OFF);
    float2* vpart = (float2*)(ws + VPART_OFF);
    float2* y2    = (float2*)(ws + ROT_OFF);
    float2* nst2  = (float2*)(ws + NST_OFF);

    k_front<<<ROT_BLOCKS + PUMP_BLOCKS + ZERO_BLOCKS, 256, 0, stream>>>(
        cs_re, cs_im, pvel, (float4*)y2, x, pump_W, pump_b, excited, lasv, emis, cnt);
    k_coup<<<N_CELLS, 256, 0, stream>>>(y2, nbrs, lasv, nst2, emis);
    k_finall<<<CELL_BLOCKS + PRED_BLOCKS, 256, 0, stream>>>(
        nst2, lasv, emis, cav_re, cav_im, dec_W, dec_b, vpart, cnt, out);
}